// Round 5
// baseline (1531.998 us; speedup 1.0000x reference)
//
#include <hip/hip_runtime.h>
#include <stdint.h>

#define PRIME_Y 2654435761u
#define PRIME_Z 805459861u
#define HASH_MASK 524287u   // 2^19 - 1

typedef float f32x2 __attribute__((ext_vector_type(2)));
typedef float f32x4 __attribute__((ext_vector_type(4)));

__constant__ float c_scales[16] = {
    15.f, 31.f, 63.f, 127.f, 255.f, 511.f, 1023.f, 2047.f,
    4095.f, 8191.f, 16383.f, 32767.f, 65535.f, 131071.f, 262143.f, 524287.f};
__constant__ uint32_t c_offsets[16] = {
    0u, 4913u, 40850u, 315475u, 839763u, 1364051u, 1888339u, 2412627u,
    2936915u, 3461203u, 3985491u, 4509779u, 5034067u, 5558355u, 6082643u, 6606931u};
__constant__ uint32_t c_strides[3] = {17u, 33u, 65u};

// ---- Pass 1: all 16 levels, level-major; dump blocked [chunk][16][256] ----
__global__ __launch_bounds__(256) void pass1_kernel(
    const float* __restrict__ in,    // [N,3]
    const float* __restrict__ emb,   // [T,2]
    f32x2* __restrict__ dump,        // [chunks][16][256]
    int N, int chunks)
{
    const int bid = blockIdx.x;
    const int level = bid / chunks;                 // level-major dispatch order
    const int chunk = bid - level * chunks;
    const int i = chunk * 256 + threadIdx.x;
    if (i >= N) return;

    // NT input loads: stream-once data, don't evict the level table from L2
    const float px = __builtin_nontemporal_load(&in[3 * i + 0]);
    const float py = __builtin_nontemporal_load(&in[3 * i + 1]);
    const float pz = __builtin_nontemporal_load(&in[3 * i + 2]);
    const float x = (px + 1.0f) * 0.5f;
    const float y = (py + 1.0f) * 0.5f;
    const float z = (pz + 1.0f) * 0.5f;

    const float scale = c_scales[level];
    const uint32_t off = c_offsets[level];

    const float posx = __fadd_rn(__fmul_rn(x, scale), 0.5f);
    const float posy = __fadd_rn(__fmul_rn(y, scale), 0.5f);
    const float posz = __fadd_rn(__fmul_rn(z, scale), 0.5f);

    const float gx = floorf(posx), gy = floorf(posy), gz = floorf(posz);
    const float fx = posx - gx, fy = posy - gy, fz = posz - gz;
    const uint32_t bx = (uint32_t)gx, by = (uint32_t)gy, bz = (uint32_t)gz;

    const float wx0 = 1.0f - fx, wx1 = fx;
    const float wy0 = 1.0f - fy, wy1 = fy;
    const float wz0 = 1.0f - fz, wz1 = fz;
    const float wxy00 = wx0 * wy0, wxy10 = wx1 * wy0;
    const float wxy01 = wx0 * wy1, wxy11 = wx1 * wy1;

    uint32_t idx[8];
    if (level < 3) {   // wave-uniform branch (level is per-block)
        const uint32_t s = c_strides[level];
        const uint32_t s2 = s * s;
        const uint32_t r0 = by * s + bz * s2;
        const uint32_t r1 = r0 + s;
        const uint32_t r2 = r0 + s2;
        const uint32_t r3 = r1 + s2;
        idx[0] = bx + r0; idx[1] = bx + 1 + r0;
        idx[2] = bx + r1; idx[3] = bx + 1 + r1;
        idx[4] = bx + r2; idx[5] = bx + 1 + r2;
        idx[6] = bx + r3; idx[7] = bx + 1 + r3;
    } else {
        const uint32_t hy0 = by * PRIME_Y, hy1 = hy0 + PRIME_Y;
        const uint32_t hz0 = bz * PRIME_Z, hz1 = hz0 + PRIME_Z;
        idx[0] = (bx ^ hy0 ^ hz0) & HASH_MASK;
        idx[1] = ((bx + 1) ^ hy0 ^ hz0) & HASH_MASK;
        idx[2] = (bx ^ hy1 ^ hz0) & HASH_MASK;
        idx[3] = ((bx + 1) ^ hy1 ^ hz0) & HASH_MASK;
        idx[4] = (bx ^ hy0 ^ hz1) & HASH_MASK;
        idx[5] = ((bx + 1) ^ hy0 ^ hz1) & HASH_MASK;
        idx[6] = (bx ^ hy1 ^ hz1) & HASH_MASK;
        idx[7] = ((bx + 1) ^ hy1 ^ hz1) & HASH_MASK;
    }

    const float w[8] = {
        wxy00 * wz0, wxy10 * wz0, wxy01 * wz0, wxy11 * wz0,
        wxy00 * wz1, wxy10 * wz1, wxy01 * wz1, wxy11 * wz1};

    const f32x2* __restrict__ e2 = reinterpret_cast<const f32x2*>(emb);

    f32x2 e[8];
#pragma unroll
    for (int c = 0; c < 8; ++c) e[c] = e2[idx[c] + off];

    float f0 = 0.0f, f1 = 0.0f;
#pragma unroll
    for (int c = 0; c < 8; ++c) {
        f0 += w[c] * e[c].x;
        f1 += w[c] * e[c].y;
    }

    f32x2 r; r.x = f0; r.y = f1;
    __builtin_nontemporal_store(r, &dump[((size_t)chunk * 16 + level) * 256 + threadIdx.x]);
}

// ---- Pass 2: pure blocked transpose dump -> out[N][32] ----
__global__ __launch_bounds__(256) void pass2_kernel(
    const f32x2* __restrict__ dump,  // [chunks][16][256]
    float* __restrict__ out, int N)
{
    const int c = blockIdx.x;
    const int t = threadIdx.x;
    const int i = c * 256 + t;
    if (i >= N) return;

    float v[32];
#pragma unroll
    for (int l = 0; l < 16; ++l) {
        f32x2 f = __builtin_nontemporal_load(&dump[((size_t)c * 16 + l) * 256 + t]);
        v[2 * l + 0] = f.x;
        v[2 * l + 1] = f.y;
    }

    f32x4* __restrict__ o4 = reinterpret_cast<f32x4*>(out + (size_t)i * 32);
#pragma unroll
    for (int q = 0; q < 8; ++q) {
        f32x4 u;
        u.x = v[4 * q + 0];
        u.y = v[4 * q + 1];
        u.z = v[4 * q + 2];
        u.w = v[4 * q + 3];
        __builtin_nontemporal_store(u, &o4[q]);
    }
}

// ---- Fallback: fused single-pass (if ws too small) ----
__global__ __launch_bounds__(256) void hash_encode_fused_kernel(
    const float* __restrict__ in,
    const float* __restrict__ emb,
    float* __restrict__ out,
    int N)
{
    const int i = blockIdx.x * 256 + threadIdx.x;
    if (i >= N) return;

    const float x = (in[3 * i + 0] + 1.0f) * 0.5f;
    const float y = (in[3 * i + 1] + 1.0f) * 0.5f;
    const float z = (in[3 * i + 2] + 1.0f) * 0.5f;

    const f32x2* __restrict__ e2 = reinterpret_cast<const f32x2*>(emb);
    float acc[32];

#pragma unroll
    for (int l = 0; l < 16; ++l) {
        const float scale = c_scales[l];
        const uint32_t off = c_offsets[l];
        const float posx = __fadd_rn(__fmul_rn(x, scale), 0.5f);
        const float posy = __fadd_rn(__fmul_rn(y, scale), 0.5f);
        const float posz = __fadd_rn(__fmul_rn(z, scale), 0.5f);
        const float gx = floorf(posx), gy = floorf(posy), gz = floorf(posz);
        const float fx = posx - gx, fy = posy - gy, fz = posz - gz;
        const uint32_t bx = (uint32_t)gx, by = (uint32_t)gy, bz = (uint32_t)gz;
        const float wx0 = 1.0f - fx, wx1 = fx;
        const float wy0 = 1.0f - fy, wy1 = fy;
        const float wz0 = 1.0f - fz, wz1 = fz;
        const float wxy00 = wx0 * wy0, wxy10 = wx1 * wy0;
        const float wxy01 = wx0 * wy1, wxy11 = wx1 * wy1;

        uint32_t idx[8];
        if (l < 3) {
            const uint32_t s = c_strides[l];
            const uint32_t s2 = s * s;
            const uint32_t r0 = by * s + bz * s2;
            const uint32_t r1 = r0 + s;
            const uint32_t r2 = r0 + s2;
            const uint32_t r3 = r1 + s2;
            idx[0] = bx + r0; idx[1] = bx + 1 + r0;
            idx[2] = bx + r1; idx[3] = bx + 1 + r1;
            idx[4] = bx + r2; idx[5] = bx + 1 + r2;
            idx[6] = bx + r3; idx[7] = bx + 1 + r3;
        } else {
            const uint32_t hy0 = by * PRIME_Y, hy1 = hy0 + PRIME_Y;
            const uint32_t hz0 = bz * PRIME_Z, hz1 = hz0 + PRIME_Z;
            idx[0] = (bx ^ hy0 ^ hz0) & HASH_MASK;
            idx[1] = ((bx + 1) ^ hy0 ^ hz0) & HASH_MASK;
            idx[2] = (bx ^ hy1 ^ hz0) & HASH_MASK;
            idx[3] = ((bx + 1) ^ hy1 ^ hz0) & HASH_MASK;
            idx[4] = (bx ^ hy0 ^ hz1) & HASH_MASK;
            idx[5] = ((bx + 1) ^ hy0 ^ hz1) & HASH_MASK;
            idx[6] = (bx ^ hy1 ^ hz1) & HASH_MASK;
            idx[7] = ((bx + 1) ^ hy1 ^ hz1) & HASH_MASK;
        }

        const float w[8] = {
            wxy00 * wz0, wxy10 * wz0, wxy01 * wz0, wxy11 * wz0,
            wxy00 * wz1, wxy10 * wz1, wxy01 * wz1, wxy11 * wz1};

        f32x2 e[8];
#pragma unroll
        for (int cc = 0; cc < 8; ++cc) e[cc] = e2[idx[cc] + off];

        float f0 = 0.0f, f1 = 0.0f;
#pragma unroll
        for (int cc = 0; cc < 8; ++cc) { f0 += w[cc] * e[cc].x; f1 += w[cc] * e[cc].y; }

        acc[2 * l + 0] = f0;
        acc[2 * l + 1] = f1;
    }

    f32x4* __restrict__ o4 = reinterpret_cast<f32x4*>(out + (size_t)i * 32);
#pragma unroll
    for (int q = 0; q < 8; ++q) {
        f32x4 v;
        v.x = acc[4 * q + 0];
        v.y = acc[4 * q + 1];
        v.z = acc[4 * q + 2];
        v.w = acc[4 * q + 3];
        o4[q] = v;
    }
}

extern "C" void kernel_launch(void* const* d_in, const int* in_sizes, int n_in,
                              void* d_out, int out_size, void* d_ws, size_t ws_size,
                              hipStream_t stream) {
    const float* in = (const float*)d_in[0];
    const float* emb = (const float*)d_in[1];
    float* out = (float*)d_out;
    const int N = in_sizes[0] / 3;
    const int chunks = (N + 255) / 256;

    const size_t dump_f2 = (size_t)chunks * 16 * 256;            // f32x2 units
    const size_t ws_needed = dump_f2 * sizeof(f32x2);            // 256 MiB at N=2^21

    if (ws_size >= ws_needed) {
        f32x2* dump = (f32x2*)d_ws;
        pass1_kernel<<<16 * chunks, 256, 0, stream>>>(in, emb, dump, N, chunks);
        pass2_kernel<<<chunks, 256, 0, stream>>>(dump, out, N);
    } else {
        hash_encode_fused_kernel<<<chunks, 256, 0, stream>>>(in, emb, out, N);
    }
}

// Round 6
// 893.207 us; speedup vs baseline: 1.7152x; 1.7152x over previous
//
#include <hip/hip_runtime.h>
#include <stdint.h>

#define PRIME_Y 2654435761u
#define PRIME_Z 805459861u
#define HASH_MASK 524287u   // 2^19 - 1

typedef float f32x2 __attribute__((ext_vector_type(2)));
typedef float f32x4 __attribute__((ext_vector_type(4)));

__constant__ float c_scales[16] = {
    15.f, 31.f, 63.f, 127.f, 255.f, 511.f, 1023.f, 2047.f,
    4095.f, 8191.f, 16383.f, 32767.f, 65535.f, 131071.f, 262143.f, 524287.f};
__constant__ uint32_t c_offsets[16] = {
    0u, 4913u, 40850u, 315475u, 839763u, 1364051u, 1888339u, 2412627u,
    2936915u, 3461203u, 3985491u, 4509779u, 5034067u, 5558355u, 6082643u, 6606931u};
__constant__ uint32_t c_strides[3] = {17u, 33u, 65u};

// ---- Pass 1: hashed levels 3..15, level-major; dump blocked [chunk][13][256] ----
__global__ __launch_bounds__(256) void pass1_kernel(
    const float* __restrict__ in,    // [N,3]
    const float* __restrict__ emb,   // [T,2]
    f32x2* __restrict__ dump,        // [chunks][13][256]
    int N, int chunks)
{
    const int bid = blockIdx.x;
    const int lev_i = bid / chunks;                 // 0..12 -> level lev_i+3
    const int chunk = bid - lev_i * chunks;
    const int i = chunk * 256 + threadIdx.x;
    if (i >= N) return;
    const int level = lev_i + 3;

    // NT input loads: stream-once data, don't evict the level table from L2
    const float px = __builtin_nontemporal_load(&in[3 * i + 0]);
    const float py = __builtin_nontemporal_load(&in[3 * i + 1]);
    const float pz = __builtin_nontemporal_load(&in[3 * i + 2]);
    const float x = (px + 1.0f) * 0.5f;
    const float y = (py + 1.0f) * 0.5f;
    const float z = (pz + 1.0f) * 0.5f;

    const float scale = c_scales[level];
    const uint32_t off = c_offsets[level];

    const float posx = __fadd_rn(__fmul_rn(x, scale), 0.5f);
    const float posy = __fadd_rn(__fmul_rn(y, scale), 0.5f);
    const float posz = __fadd_rn(__fmul_rn(z, scale), 0.5f);

    const float gx = floorf(posx), gy = floorf(posy), gz = floorf(posz);
    const float fx = posx - gx, fy = posy - gy, fz = posz - gz;
    const uint32_t bx = (uint32_t)gx, by = (uint32_t)gy, bz = (uint32_t)gz;

    const float wx0 = 1.0f - fx, wx1 = fx;
    const float wy0 = 1.0f - fy, wy1 = fy;
    const float wz0 = 1.0f - fz, wz1 = fz;
    const float wxy00 = wx0 * wy0, wxy10 = wx1 * wy0;
    const float wxy01 = wx0 * wy1, wxy11 = wx1 * wy1;

    const uint32_t hy0 = by * PRIME_Y, hy1 = hy0 + PRIME_Y;
    const uint32_t hz0 = bz * PRIME_Z, hz1 = hz0 + PRIME_Z;

    uint32_t idx[8];
    idx[0] = (bx ^ hy0 ^ hz0) & HASH_MASK;
    idx[1] = ((bx + 1) ^ hy0 ^ hz0) & HASH_MASK;
    idx[2] = (bx ^ hy1 ^ hz0) & HASH_MASK;
    idx[3] = ((bx + 1) ^ hy1 ^ hz0) & HASH_MASK;
    idx[4] = (bx ^ hy0 ^ hz1) & HASH_MASK;
    idx[5] = ((bx + 1) ^ hy0 ^ hz1) & HASH_MASK;
    idx[6] = (bx ^ hy1 ^ hz1) & HASH_MASK;
    idx[7] = ((bx + 1) ^ hy1 ^ hz1) & HASH_MASK;

    const float w[8] = {
        wxy00 * wz0, wxy10 * wz0, wxy01 * wz0, wxy11 * wz0,
        wxy00 * wz1, wxy10 * wz1, wxy01 * wz1, wxy11 * wz1};

    const f32x2* __restrict__ e2 = reinterpret_cast<const f32x2*>(emb);

    f32x2 e[8];
#pragma unroll
    for (int c = 0; c < 8; ++c) e[c] = e2[idx[c] + off];

    float f0 = 0.0f, f1 = 0.0f;
#pragma unroll
    for (int c = 0; c < 8; ++c) {
        f0 += w[c] * e[c].x;
        f1 += w[c] * e[c].y;
    }

    f32x2 r; r.x = f0; r.y = f1;
    // coalesced full-line block write — NT ok, keeps L2 for the table
    __builtin_nontemporal_store(r, &dump[((size_t)chunk * 13 + lev_i) * 256 + threadIdx.x]);
}

// ---- Pass 2: fused dense levels 0..2 + transpose dump -> out[N][32] (PLAIN mem ops) ----
__global__ __launch_bounds__(256) void pass2_kernel(
    const float* __restrict__ in,
    const float* __restrict__ emb,
    const f32x2* __restrict__ dump,  // [chunks][13][256]
    float* __restrict__ out, int N)
{
    const int c = blockIdx.x;
    const int t = threadIdx.x;
    const int i = c * 256 + t;
    if (i >= N) return;

    float acc[32];

    const float x = (in[3 * i + 0] + 1.0f) * 0.5f;
    const float y = (in[3 * i + 1] + 1.0f) * 0.5f;
    const float z = (in[3 * i + 2] + 1.0f) * 0.5f;

    const f32x2* __restrict__ e2 = reinterpret_cast<const f32x2*>(emb);

#pragma unroll
    for (int l = 0; l < 3; ++l) {
        const float scale = c_scales[l];
        const uint32_t off = c_offsets[l];
        const float posx = __fadd_rn(__fmul_rn(x, scale), 0.5f);
        const float posy = __fadd_rn(__fmul_rn(y, scale), 0.5f);
        const float posz = __fadd_rn(__fmul_rn(z, scale), 0.5f);
        const float gx = floorf(posx), gy = floorf(posy), gz = floorf(posz);
        const float fx = posx - gx, fy = posy - gy, fz = posz - gz;
        const uint32_t bx = (uint32_t)gx, by = (uint32_t)gy, bz = (uint32_t)gz;
        const float wx0 = 1.0f - fx, wx1 = fx;
        const float wy0 = 1.0f - fy, wy1 = fy;
        const float wz0 = 1.0f - fz, wz1 = fz;
        const float wxy00 = wx0 * wy0, wxy10 = wx1 * wy0;
        const float wxy01 = wx0 * wy1, wxy11 = wx1 * wy1;

        const uint32_t s = c_strides[l];
        const uint32_t s2 = s * s;
        const uint32_t r0 = by * s + bz * s2;
        const uint32_t r1 = r0 + s;
        const uint32_t r2 = r0 + s2;
        const uint32_t r3 = r1 + s2;
        uint32_t idx[8];
        idx[0] = bx + r0; idx[1] = bx + 1 + r0;
        idx[2] = bx + r1; idx[3] = bx + 1 + r1;
        idx[4] = bx + r2; idx[5] = bx + 1 + r2;
        idx[6] = bx + r3; idx[7] = bx + 1 + r3;

        const float w[8] = {
            wxy00 * wz0, wxy10 * wz0, wxy01 * wz0, wxy11 * wz0,
            wxy00 * wz1, wxy10 * wz1, wxy01 * wz1, wxy11 * wz1};

        f32x2 e[8];
#pragma unroll
        for (int cc = 0; cc < 8; ++cc) e[cc] = e2[idx[cc] + off];

        float f0 = 0.0f, f1 = 0.0f;
#pragma unroll
        for (int cc = 0; cc < 8; ++cc) { f0 += w[cc] * e[cc].x; f1 += w[cc] * e[cc].y; }

        acc[2 * l + 0] = f0;
        acc[2 * l + 1] = f1;
    }

#pragma unroll
    for (int li = 0; li < 13; ++li) {
        f32x2 f = dump[((size_t)c * 13 + li) * 256 + t];
        acc[2 * (li + 3) + 0] = f.x;
        acc[2 * (li + 3) + 1] = f.y;
    }

    f32x4* __restrict__ o4 = reinterpret_cast<f32x4*>(out + (size_t)i * 32);
#pragma unroll
    for (int q = 0; q < 8; ++q) {
        f32x4 v;
        v.x = acc[4 * q + 0];
        v.y = acc[4 * q + 1];
        v.z = acc[4 * q + 2];
        v.w = acc[4 * q + 3];
        o4[q] = v;   // plain store — let L2 assemble full lines
    }
}

// ---- Fallback: fused single-pass (if ws too small) ----
__global__ __launch_bounds__(256) void hash_encode_fused_kernel(
    const float* __restrict__ in,
    const float* __restrict__ emb,
    float* __restrict__ out,
    int N)
{
    const int i = blockIdx.x * 256 + threadIdx.x;
    if (i >= N) return;

    const float x = (in[3 * i + 0] + 1.0f) * 0.5f;
    const float y = (in[3 * i + 1] + 1.0f) * 0.5f;
    const float z = (in[3 * i + 2] + 1.0f) * 0.5f;

    const f32x2* __restrict__ e2 = reinterpret_cast<const f32x2*>(emb);
    float acc[32];

#pragma unroll
    for (int l = 0; l < 16; ++l) {
        const float scale = c_scales[l];
        const uint32_t off = c_offsets[l];
        const float posx = __fadd_rn(__fmul_rn(x, scale), 0.5f);
        const float posy = __fadd_rn(__fmul_rn(y, scale), 0.5f);
        const float posz = __fadd_rn(__fmul_rn(z, scale), 0.5f);
        const float gx = floorf(posx), gy = floorf(posy), gz = floorf(posz);
        const float fx = posx - gx, fy = posy - gy, fz = posz - gz;
        const uint32_t bx = (uint32_t)gx, by = (uint32_t)gy, bz = (uint32_t)gz;
        const float wx0 = 1.0f - fx, wx1 = fx;
        const float wy0 = 1.0f - fy, wy1 = fy;
        const float wz0 = 1.0f - fz, wz1 = fz;
        const float wxy00 = wx0 * wy0, wxy10 = wx1 * wy0;
        const float wxy01 = wx0 * wy1, wxy11 = wx1 * wy1;

        uint32_t idx[8];
        if (l < 3) {
            const uint32_t s = c_strides[l];
            const uint32_t s2 = s * s;
            const uint32_t r0 = by * s + bz * s2;
            const uint32_t r1 = r0 + s;
            const uint32_t r2 = r0 + s2;
            const uint32_t r3 = r1 + s2;
            idx[0] = bx + r0; idx[1] = bx + 1 + r0;
            idx[2] = bx + r1; idx[3] = bx + 1 + r1;
            idx[4] = bx + r2; idx[5] = bx + 1 + r2;
            idx[6] = bx + r3; idx[7] = bx + 1 + r3;
        } else {
            const uint32_t hy0 = by * PRIME_Y, hy1 = hy0 + PRIME_Y;
            const uint32_t hz0 = bz * PRIME_Z, hz1 = hz0 + PRIME_Z;
            idx[0] = (bx ^ hy0 ^ hz0) & HASH_MASK;
            idx[1] = ((bx + 1) ^ hy0 ^ hz0) & HASH_MASK;
            idx[2] = (bx ^ hy1 ^ hz0) & HASH_MASK;
            idx[3] = ((bx + 1) ^ hy1 ^ hz0) & HASH_MASK;
            idx[4] = (bx ^ hy0 ^ hz1) & HASH_MASK;
            idx[5] = ((bx + 1) ^ hy0 ^ hz1) & HASH_MASK;
            idx[6] = (bx ^ hy1 ^ hz1) & HASH_MASK;
            idx[7] = ((bx + 1) ^ hy1 ^ hz1) & HASH_MASK;
        }

        const float w[8] = {
            wxy00 * wz0, wxy10 * wz0, wxy01 * wz0, wxy11 * wz0,
            wxy00 * wz1, wxy10 * wz1, wxy01 * wz1, wxy11 * wz1};

        f32x2 e[8];
#pragma unroll
        for (int cc = 0; cc < 8; ++cc) e[cc] = e2[idx[cc] + off];

        float f0 = 0.0f, f1 = 0.0f;
#pragma unroll
        for (int cc = 0; cc < 8; ++cc) { f0 += w[cc] * e[cc].x; f1 += w[cc] * e[cc].y; }

        acc[2 * l + 0] = f0;
        acc[2 * l + 1] = f1;
    }

    f32x4* __restrict__ o4 = reinterpret_cast<f32x4*>(out + (size_t)i * 32);
#pragma unroll
    for (int q = 0; q < 8; ++q) {
        f32x4 v;
        v.x = acc[4 * q + 0];
        v.y = acc[4 * q + 1];
        v.z = acc[4 * q + 2];
        v.w = acc[4 * q + 3];
        o4[q] = v;
    }
}

extern "C" void kernel_launch(void* const* d_in, const int* in_sizes, int n_in,
                              void* d_out, int out_size, void* d_ws, size_t ws_size,
                              hipStream_t stream) {
    const float* in = (const float*)d_in[0];
    const float* emb = (const float*)d_in[1];
    float* out = (float*)d_out;
    const int N = in_sizes[0] / 3;
    const int chunks = (N + 255) / 256;

    const size_t dump_f2 = (size_t)chunks * 13 * 256;            // f32x2 units
    const size_t ws_needed = dump_f2 * sizeof(f32x2);            // 208 MiB at N=2^21

    if (ws_size >= ws_needed) {
        f32x2* dump = (f32x2*)d_ws;
        pass1_kernel<<<13 * chunks, 256, 0, stream>>>(in, emb, dump, N, chunks);
        pass2_kernel<<<chunks, 256, 0, stream>>>(in, emb, dump, out, N);
    } else {
        hash_encode_fused_kernel<<<chunks, 256, 0, stream>>>(in, emb, out, N);
    }
}